// Round 6
// baseline (95.673 us; speedup 1.0000x reference)
//
#include <hip/hip_runtime.h>
#include <cmath>

#define BB 64
#define KK 100
#define QQ 100
#define CC 82
#define AA 118
#define KP1 101
#define AM1 117
#define ROWF (KK * KP1)      // 10100 floats per (b,a) row
#define PAIRF (BB * AM1 * ROWF)  // 75,628,800 floats total
#define ZB 2496              // zero blocks; PAIRF/4/ZB = 7575 float4 exactly
#define ZCHUNK4 7575

typedef float vf4 __attribute__((ext_vector_type(4)));

// Kernel A: blocks [0,ZB): contiguous nontemporal float4 zero stream over
// pair_score. Blocks [ZB, ZB+BB): per-batch prep (scores/labels/boxes +
// per-query f/coef + compacted matched list) running CONCURRENTLY with the
// zero stream (no data overlap: prep writes only the small output segments
// and workspace).
__global__ __launch_bounds__(512) void fused_zero_prep(
    const float* __restrict__ logits,   // B,K,C
    const float* __restrict__ boxes_in, // B,K,4
    const float* __restrict__ actions,  // B,Q,A
    const float* __restrict__ hidx,     // B,Q,K
    const float* __restrict__ oidx,     // B,Q,K
    const int*   __restrict__ tsizes,   // B,2
    float* __restrict__ out_scores,     // B,K
    float* __restrict__ out_labels,     // B,K
    float* __restrict__ out_boxes,      // B,K,4
    float* __restrict__ out_pair,       // B,117,100,101
    int*   __restrict__ wsf,            // B,Q  flat segment id
    float* __restrict__ wsc,            // B,Q  coefficient (0 if masked out)
    int*   __restrict__ wsl,            // B,Q  compacted matched-q list
    int*   __restrict__ wsn)            // B    matched count
{
    int blk = blockIdx.x;
    int tid = threadIdx.x;

    __shared__ int   sh_h[QQ], sh_o[QQ];
    __shared__ float sh_ms[QQ], sh_labf[KK];
    __shared__ int   sh_spos[KK];
    __shared__ float sh_c[QQ];
    __shared__ int   sh_wcnt[2];

    if (blk < ZB) {
        vf4* dst = ((vf4*)out_pair) + (size_t)blk * ZCHUNK4;
        const vf4 z = {0.f, 0.f, 0.f, 0.f};
        for (int i = tid; i < ZCHUNK4; i += 512)
            __builtin_nontemporal_store(z, dst + i);
        return;
    }

    int b = blk - ZB;

    // ---- phase A: wave-partitioned per-k / per-q tasks ----
    if (tid < KK) {
        // softmax-lite: label (argmax over first 81), score; + boxes
        const float2* l2 = (const float2*)(logits + ((size_t)b * KK + tid) * CC);
        float m = -INFINITY, best = -INFINITY; int bi = 0;
        #pragma unroll
        for (int i = 0; i < CC / 2; ++i) {
            float2 p = l2[i];
            m = fmaxf(m, fmaxf(p.x, p.y));
            if (p.x > best) { best = p.x; bi = 2 * i; }
            if (2 * i + 1 < CC - 1 && p.y > best) { best = p.y; bi = 2 * i + 1; }
        }
        float denom = 0.f;
        #pragma unroll
        for (int i = 0; i < CC / 2; ++i) {
            float2 p = l2[i];
            denom += expf(p.x - m) + expf(p.y - m);
        }
        float score = expf(best - m) / denom;
        sh_labf[tid] = (float)bi;
        sh_spos[tid] = (score > 0.0f) ? 1 : 0;
        out_scores[b * KK + tid] = score;
        out_labels[b * KK + tid] = (float)bi;

        const float4 bx = *(const float4*)(boxes_in + ((size_t)b * KK + tid) * 4);
        float ihh = (float)tsizes[b * 2 + 0];
        float iww = (float)tsizes[b * 2 + 1];
        float4 ob;
        ob.x = (bx.x - 0.5f * bx.z) * iww;
        ob.y = (bx.y - 0.5f * bx.w) * ihh;
        ob.z = (bx.x + 0.5f * bx.z) * iww;
        ob.w = (bx.y + 0.5f * bx.w) * ihh;
        *(float4*)(out_boxes + ((size_t)b * KK + tid) * 4) = ob;
    } else if (tid >= 128 && tid < 128 + QQ) {
        int q = tid - 128;  // argmax hidx (first occurrence, strict >)
        const float4* rp = (const float4*)(hidx + ((size_t)b * QQ + q) * KK);
        float best = -INFINITY; int bi = 0;
        #pragma unroll
        for (int i = 0; i < KK / 4; ++i) {
            float4 r = rp[i];
            if (r.x > best) { best = r.x; bi = 4 * i; }
            if (r.y > best) { best = r.y; bi = 4 * i + 1; }
            if (r.z > best) { best = r.z; bi = 4 * i + 2; }
            if (r.w > best) { best = r.w; bi = 4 * i + 3; }
        }
        sh_h[q] = bi;
    } else if (tid >= 256 && tid < 256 + QQ) {
        int q = tid - 256;  // argmax oidx
        const float4* rp = (const float4*)(oidx + ((size_t)b * QQ + q) * KK);
        float best = -INFINITY; int bi = 0;
        #pragma unroll
        for (int i = 0; i < KK / 4; ++i) {
            float4 r = rp[i];
            if (r.x > best) { best = r.x; bi = 4 * i; }
            if (r.y > best) { best = r.y; bi = 4 * i + 1; }
            if (r.z > best) { best = r.z; bi = 4 * i + 2; }
            if (r.w > best) { best = r.w; bi = 4 * i + 3; }
        }
        sh_o[q] = bi;
    } else if (tid >= 384 && tid < 384 + QQ) {
        int q = tid - 384;  // ms = 1 - sigmoid(last action)
        float x = actions[((size_t)b * QQ + q) * AA + (AA - 1)];
        sh_ms[q] = 1.f - 1.f / (1.f + expf(-x));
    }
    __syncthreads();

    // ---- phase B: winner-per-segment + masked coefficient ----
    if (tid < QQ) {
        int hh = sh_h[tid], oo = sh_o[tid];
        int f = hh * KP1 + oo;
        float myms = sh_ms[tid];
        bool winf = true;
        for (int q = 0; q < QQ; ++q) {
            if (sh_h[q] * KP1 + sh_o[q] == f) {
                float m2 = sh_ms[q];
                if (m2 > myms || (m2 == myms && q < tid)) { winf = false; break; }
            }
        }
        float hm = (sh_labf[hh] == 1.0f && sh_spos[hh]) ? 1.f : 0.f;
        float om = sh_spos[oo] ? 1.f : 0.f;
        float c = myms * (winf ? 2.f : 1.f) * hm * om;
        sh_c[tid] = c;
        wsf[b * QQ + tid] = f;
        wsc[b * QQ + tid] = c;
    }
    __syncthreads();

    // ---- phase C: ballot-compact matched queries (c != 0) ----
    if (tid < 128) {
        bool flag = (tid < QQ) && (sh_c[tid] != 0.f);
        unsigned long long bal = __ballot(flag);
        if ((tid & 63) == 0) sh_wcnt[tid >> 6] = __popcll(bal);
    }
    __syncthreads();
    if (tid < 128) {
        bool flag = (tid < QQ) && (sh_c[tid] != 0.f);
        unsigned long long bal = __ballot(flag);
        int base = (tid >> 6) ? sh_wcnt[0] : 0;
        if (flag) {
            int pos = base + __popcll(bal & ((1ull << (tid & 63)) - 1ull));
            wsl[b * QQ + pos] = tid;
        }
        if (tid == 0) wsn[b] = sh_wcnt[0] + sh_wcnt[1];
    }
}

// Kernel B: tiny fixup. Per batch: n_matched*117 atomicAdds (expected ~150).
__global__ __launch_bounds__(256) void fixup_kernel(
    const float* __restrict__ actions, // B,Q,A
    const int*   __restrict__ wsf,
    const float* __restrict__ wsc,
    const int*   __restrict__ wsl,
    const int*   __restrict__ wsn,
    float* __restrict__ out_pair)      // B,117,100,101
{
    int b = blockIdx.x;
    int tid = threadIdx.x;
    int n = wsn[b];
    int total = n * AM1;
    for (int t = tid; t < total; t += 256) {
        int j = t / AM1;
        int a = t - j * AM1;
        int q = wsl[b * QQ + j];
        float c = wsc[b * QQ + q];
        int f = wsf[b * QQ + q];
        float x = actions[((size_t)b * QQ + q) * AA + a];
        float val = c / (1.f + expf(-x));
        atomicAdd(out_pair + ((size_t)(b * AM1 + a)) * ROWF + f, val);
    }
}

extern "C" void kernel_launch(void* const* d_in, const int* in_sizes, int n_in,
                              void* d_out, int out_size, void* d_ws, size_t ws_size,
                              hipStream_t stream) {
    const float* pred_logits  = (const float*)d_in[0];
    const float* pred_boxes   = (const float*)d_in[1];
    const float* pred_actions = (const float*)d_in[2];
    const float* pred_hidx    = (const float*)d_in[3];
    const float* pred_oidx    = (const float*)d_in[4];
    const int*   target_sizes = (const int*)d_in[5];

    float* out = (float*)d_out;
    float* out_scores = out;                // B*K
    float* out_labels = out + BB * KK;      // B*K
    float* out_boxes  = out + 2 * BB * KK;  // B*K*4
    float* out_pair   = out + 6 * BB * KK;  // B*117*100*101

    int*   wsf = (int*)d_ws;                 // B*Q
    float* wsc = (float*)(wsf + BB * QQ);    // B*Q
    int*   wsl = (int*)(wsc + BB * QQ);      // B*Q
    int*   wsn = wsl + BB * QQ;              // B

    fused_zero_prep<<<ZB + BB, 512, 0, stream>>>(
        pred_logits, pred_boxes, pred_actions, pred_hidx, pred_oidx,
        target_sizes, out_scores, out_labels, out_boxes, out_pair,
        wsf, wsc, wsl, wsn);

    fixup_kernel<<<BB, 256, 0, stream>>>(pred_actions, wsf, wsc, wsl, wsn,
                                         out_pair);
}

// Round 7
// 55.987 us; speedup vs baseline: 1.7089x; 1.7089x over previous
//
#include <hip/hip_runtime.h>
#include <cmath>

#define BB 64
#define KK 100
#define QQ 100
#define CC 82
#define AA 118
#define KP1 101
#define AM1 117
#define ROWF (KK * KP1)          // 10100 floats per (b,a) row
#define PAIRF (BB * AM1 * ROWF)  // 75,628,800 floats total
#define PB 64                    // prep blocks (FIRST in grid, overlap zeros)
#define ZB 2496                  // zero blocks; PAIRF/4/ZB = 7575 float4 exactly
#define ZCHUNK4 7575

typedef float vf4 __attribute__((ext_vector_type(4)));

// Kernel A: blocks [0,PB): per-batch prep (scores/labels/boxes + per-query
// f/coef + compacted matched list) — launched FIRST so their latency hides
// under the zero stream. Blocks [PB, PB+ZB): contiguous regular-store float4
// zero stream over pair_score (fill-shaped: the rocclr fill hits 6.9 TB/s
// with plain stores; nontemporal measured ~2x slower in round 6).
__global__ __launch_bounds__(512) void fused_prep_zero(
    const float* __restrict__ logits,   // B,K,C
    const float* __restrict__ boxes_in, // B,K,4
    const float* __restrict__ actions,  // B,Q,A
    const float* __restrict__ hidx,     // B,Q,K
    const float* __restrict__ oidx,     // B,Q,K
    const int*   __restrict__ tsizes,   // B,2
    float* __restrict__ out_scores,     // B,K
    float* __restrict__ out_labels,     // B,K
    float* __restrict__ out_boxes,      // B,K,4
    float* __restrict__ out_pair,       // B,117,100,101
    int*   __restrict__ wsf,            // B,Q  flat segment id
    float* __restrict__ wsc,            // B,Q  coefficient (0 if masked out)
    int*   __restrict__ wsl,            // B,Q  compacted matched-q list
    int*   __restrict__ wsn)            // B    matched count
{
    int blk = blockIdx.x;
    int tid = threadIdx.x;

    __shared__ int   sh_h[QQ], sh_o[QQ];
    __shared__ float sh_ms[QQ], sh_labf[KK];
    __shared__ int   sh_spos[KK];
    __shared__ float sh_c[QQ];
    __shared__ int   sh_wcnt[2];

    if (blk >= PB) {
        vf4* dst = ((vf4*)out_pair) + (size_t)(blk - PB) * ZCHUNK4;
        const vf4 z = {0.f, 0.f, 0.f, 0.f};
        for (int i = tid; i < ZCHUNK4; i += 512)
            dst[i] = z;
        return;
    }

    int b = blk;

    // ---- phase A: wave-partitioned per-k / per-q tasks ----
    if (tid < KK) {
        // softmax-lite: label (argmax over first 81), score; + boxes
        const float2* l2 = (const float2*)(logits + ((size_t)b * KK + tid) * CC);
        float m = -INFINITY, best = -INFINITY; int bi = 0;
        #pragma unroll
        for (int i = 0; i < CC / 2; ++i) {
            float2 p = l2[i];
            m = fmaxf(m, fmaxf(p.x, p.y));
            if (p.x > best) { best = p.x; bi = 2 * i; }
            if (2 * i + 1 < CC - 1 && p.y > best) { best = p.y; bi = 2 * i + 1; }
        }
        float denom = 0.f;
        #pragma unroll
        for (int i = 0; i < CC / 2; ++i) {
            float2 p = l2[i];
            denom += expf(p.x - m) + expf(p.y - m);
        }
        float score = expf(best - m) / denom;
        sh_labf[tid] = (float)bi;
        sh_spos[tid] = (score > 0.0f) ? 1 : 0;
        out_scores[b * KK + tid] = score;
        out_labels[b * KK + tid] = (float)bi;

        const float4 bx = *(const float4*)(boxes_in + ((size_t)b * KK + tid) * 4);
        float ihh = (float)tsizes[b * 2 + 0];
        float iww = (float)tsizes[b * 2 + 1];
        float4 ob;
        ob.x = (bx.x - 0.5f * bx.z) * iww;
        ob.y = (bx.y - 0.5f * bx.w) * ihh;
        ob.z = (bx.x + 0.5f * bx.z) * iww;
        ob.w = (bx.y + 0.5f * bx.w) * ihh;
        *(float4*)(out_boxes + ((size_t)b * KK + tid) * 4) = ob;
    } else if (tid >= 128 && tid < 128 + QQ) {
        int q = tid - 128;  // argmax hidx (first occurrence, strict >)
        const float4* rp = (const float4*)(hidx + ((size_t)b * QQ + q) * KK);
        float best = -INFINITY; int bi = 0;
        #pragma unroll
        for (int i = 0; i < KK / 4; ++i) {
            float4 r = rp[i];
            if (r.x > best) { best = r.x; bi = 4 * i; }
            if (r.y > best) { best = r.y; bi = 4 * i + 1; }
            if (r.z > best) { best = r.z; bi = 4 * i + 2; }
            if (r.w > best) { best = r.w; bi = 4 * i + 3; }
        }
        sh_h[q] = bi;
    } else if (tid >= 256 && tid < 256 + QQ) {
        int q = tid - 256;  // argmax oidx
        const float4* rp = (const float4*)(oidx + ((size_t)b * QQ + q) * KK);
        float best = -INFINITY; int bi = 0;
        #pragma unroll
        for (int i = 0; i < KK / 4; ++i) {
            float4 r = rp[i];
            if (r.x > best) { best = r.x; bi = 4 * i; }
            if (r.y > best) { best = r.y; bi = 4 * i + 1; }
            if (r.z > best) { best = r.z; bi = 4 * i + 2; }
            if (r.w > best) { best = r.w; bi = 4 * i + 3; }
        }
        sh_o[q] = bi;
    } else if (tid >= 384 && tid < 384 + QQ) {
        int q = tid - 384;  // ms = 1 - sigmoid(last action)
        float x = actions[((size_t)b * QQ + q) * AA + (AA - 1)];
        sh_ms[q] = 1.f - 1.f / (1.f + expf(-x));
    }
    __syncthreads();

    // ---- phase B: winner-per-segment + masked coefficient ----
    if (tid < QQ) {
        int hh = sh_h[tid], oo = sh_o[tid];
        int f = hh * KP1 + oo;
        float myms = sh_ms[tid];
        bool winf = true;
        for (int q = 0; q < QQ; ++q) {
            if (sh_h[q] * KP1 + sh_o[q] == f) {
                float m2 = sh_ms[q];
                if (m2 > myms || (m2 == myms && q < tid)) { winf = false; break; }
            }
        }
        float hm = (sh_labf[hh] == 1.0f && sh_spos[hh]) ? 1.f : 0.f;
        float om = sh_spos[oo] ? 1.f : 0.f;
        float c = myms * (winf ? 2.f : 1.f) * hm * om;
        sh_c[tid] = c;
        wsf[b * QQ + tid] = f;
        wsc[b * QQ + tid] = c;
    }
    __syncthreads();

    // ---- phase C: ballot-compact matched queries (c != 0) ----
    if (tid < 128) {
        bool flag = (tid < QQ) && (sh_c[tid] != 0.f);
        unsigned long long bal = __ballot(flag);
        if ((tid & 63) == 0) sh_wcnt[tid >> 6] = __popcll(bal);
    }
    __syncthreads();
    if (tid < 128) {
        bool flag = (tid < QQ) && (sh_c[tid] != 0.f);
        unsigned long long bal = __ballot(flag);
        int base = (tid >> 6) ? sh_wcnt[0] : 0;
        if (flag) {
            int pos = base + __popcll(bal & ((1ull << (tid & 63)) - 1ull));
            wsl[b * QQ + pos] = tid;
        }
        if (tid == 0) wsn[b] = sh_wcnt[0] + sh_wcnt[1];
    }
}

// Kernel B: tiny fixup. Per batch: n_matched*117 atomicAdds (expected ~150).
__global__ __launch_bounds__(256) void fixup_kernel(
    const float* __restrict__ actions, // B,Q,A
    const int*   __restrict__ wsf,
    const float* __restrict__ wsc,
    const int*   __restrict__ wsl,
    const int*   __restrict__ wsn,
    float* __restrict__ out_pair)      // B,117,100,101
{
    int b = blockIdx.x;
    int tid = threadIdx.x;
    int n = wsn[b];
    int total = n * AM1;
    for (int t = tid; t < total; t += 256) {
        int j = t / AM1;
        int a = t - j * AM1;
        int q = wsl[b * QQ + j];
        float c = wsc[b * QQ + q];
        int f = wsf[b * QQ + q];
        float x = actions[((size_t)b * QQ + q) * AA + a];
        float val = c / (1.f + expf(-x));
        atomicAdd(out_pair + ((size_t)(b * AM1 + a)) * ROWF + f, val);
    }
}

extern "C" void kernel_launch(void* const* d_in, const int* in_sizes, int n_in,
                              void* d_out, int out_size, void* d_ws, size_t ws_size,
                              hipStream_t stream) {
    const float* pred_logits  = (const float*)d_in[0];
    const float* pred_boxes   = (const float*)d_in[1];
    const float* pred_actions = (const float*)d_in[2];
    const float* pred_hidx    = (const float*)d_in[3];
    const float* pred_oidx    = (const float*)d_in[4];
    const int*   target_sizes = (const int*)d_in[5];

    float* out = (float*)d_out;
    float* out_scores = out;                // B*K
    float* out_labels = out + BB * KK;      // B*K
    float* out_boxes  = out + 2 * BB * KK;  // B*K*4
    float* out_pair   = out + 6 * BB * KK;  // B*117*100*101

    int*   wsf = (int*)d_ws;                 // B*Q
    float* wsc = (float*)(wsf + BB * QQ);    // B*Q
    int*   wsl = (int*)(wsc + BB * QQ);      // B*Q
    int*   wsn = wsl + BB * QQ;              // B

    fused_prep_zero<<<PB + ZB, 512, 0, stream>>>(
        pred_logits, pred_boxes, pred_actions, pred_hidx, pred_oidx,
        target_sizes, out_scores, out_labels, out_boxes, out_pair,
        wsf, wsc, wsl, wsn);

    fixup_kernel<<<BB, 256, 0, stream>>>(pred_actions, wsf, wsc, wsl, wsn,
                                         out_pair);
}